// Round 5
// baseline (175.330 us; speedup 1.0000x reference)
//
#include <hip/hip_runtime.h>

// FTDisentangledMHA: B=8, S=512, D=1024, H=16, Wd=64, MAX_REL=512 (span==S)
// scores(i,j) = scale*(q_i.k_j + q_i.pk[i-j+511] + k_j.pq[i-j+511]); no clip, mask all-true.
// q,pq pre-scaled by scale*log2e; softmax = exp2 with fixed max M=3.
// R5: gemm uses BK=64 + counted vmcnt(8) 2-deep pipeline (raw s_barrier, no drain);
//     bias_sum emits ONE summed fragment-ordered buffer SBf (c2p+p2c), halving traffic.

typedef __bf16 bf16_t;
typedef __bf16 bf16x8 __attribute__((ext_vector_type(8)));
typedef __bf16 bf16x4 __attribute__((ext_vector_type(4)));
typedef float  f32x4  __attribute__((ext_vector_type(4)));

#define MFMA16(a, b, c) __builtin_amdgcn_mfma_f32_16x16x32_bf16((a), (b), (c), 0, 0, 0)
#define S2SCALE 0.10411754f   // (1/sqrt(192)) * log2(e)
#define MCONST  4.3280851f    // 3 * log2(e)

__device__ __forceinline__ void gload_lds16(const bf16_t* g, bf16_t* lds) {
  __builtin_amdgcn_global_load_lds(
      (const __attribute__((address_space(1))) void*)g,
      (__attribute__((address_space(3))) void*)lds, 16, 0, 0);
}

// chunk swizzle for row-major [rows][64] bf16 tiles staged as 16B chunks
__device__ __forceinline__ int kchunk(int row, int kg) {
  return row * 8 + (kg ^ (row & 7));
}

// ---------------------------------------------------------------- fp32 -> bf16 (all 5 arrays)
__global__ __launch_bounds__(256) void cvt_all(
    const float* __restrict__ x, const float* __restrict__ rel,
    const float* __restrict__ wq, const float* __restrict__ wk, const float* __restrict__ wv,
    bf16_t* __restrict__ out) {
  const size_t i = ((size_t)blockIdx.x * 256 + threadIdx.x) * 4;
  const float* src; size_t off;
  if (i < 4194304) { src = x; off = i; }
  else {
    size_t j = i - 4194304; int sel = (int)(j >> 20); off = j & 1048575;
    src = sel == 0 ? wq : sel == 1 ? wk : sel == 2 ? wv : rel;
  }
  float4 v = *reinterpret_cast<const float4*>(src + off);
  bf16x4 o;
  o[0] = (bf16_t)v.x; o[1] = (bf16_t)v.y; o[2] = (bf16_t)v.z; o[3] = (bf16_t)v.w;
  *reinterpret_cast<bf16x4*>(out + i) = o;
}

// ------------------------------------------------- fused projection GEMMs
// BK=64, 2-deep prefetch pipeline with counted vmcnt (never 0 in main loop).
__global__ __launch_bounds__(256) void gemm_all(
    const bf16_t* __restrict__ xb, const bf16_t* __restrict__ reb,
    const bf16_t* __restrict__ wqb, const bf16_t* __restrict__ wkb, const bf16_t* __restrict__ wvb,
    const float* __restrict__ bq, const float* __restrict__ bk, const float* __restrict__ bv,
    bf16_t* __restrict__ qo, bf16_t* __restrict__ ko, bf16_t* __restrict__ vo,
    bf16_t* __restrict__ pko, bf16_t* __restrict__ pqo) {
  const int bid0 = blockIdx.x;
  const int bid = (bid0 & 7) * 112 + (bid0 >> 3);  // 896 = 8*112, bijective XCD chunks
  int z, bx, by;
  if (bid < 768) { z = bid >> 8; int lcl = bid & 255; bx = lcl & 31; by = lcl >> 5; }
  else { int lcl = bid - 768; z = 3 + (lcl >> 6); lcl &= 63; bx = lcl & 7; by = lcl >> 3; }
  const bf16_t* A; const bf16_t* Bw; const float* bias; bf16_t* C; float sc;
  if      (z == 0) { A = xb;  Bw = wqb; bias = bq; C = qo;  sc = S2SCALE; }
  else if (z == 1) { A = xb;  Bw = wkb; bias = bk; C = ko;  sc = 1.f;     }
  else if (z == 2) { A = xb;  Bw = wvb; bias = bv; C = vo;  sc = 1.f;     }
  else if (z == 3) { A = reb; Bw = wkb; bias = bk; C = pko; sc = 1.f;     }
  else             { A = reb; Bw = wqb; bias = bq; C = pqo; sc = S2SCALE; }

  __shared__ bf16_t As[2][8192];   // [kg 8][row 128][8]
  __shared__ bf16_t Bs[2][8192];
  const int tid = threadIdx.x;
  const int l = tid & 63;
  const int wid = tid >> 6;
  const int wr = wid >> 1, wc = wid & 1;
  const int li = l & 15, gr = l >> 4;
  const int m0 = bx * 128, n0 = by * 128;

  const bf16_t* Ab = A + (size_t)m0 * 1024;
  const bf16_t* Bb = Bw + (size_t)n0 * 1024;

  f32x4 acc[4][4] = {};

  // stage K-tile t (64 wide) into buffer buf: 8 gload_lds per wave
#define STAGE(t, buf)                                                              \
  {                                                                                \
    const int k0_ = (t) * 64;                                                      \
    _Pragma("unroll")                                                              \
    for (int i_ = 0; i_ < 4; ++i_) {                                               \
      const int c_ = i_ * 256 + tid;                                               \
      const int row_ = c_ & 127, kg_ = c_ >> 7;                                    \
      gload_lds16(Ab + (size_t)row_ * 1024 + k0_ + kg_ * 8, &As[buf][c_ * 8]);     \
    }                                                                              \
    _Pragma("unroll")                                                              \
    for (int i_ = 0; i_ < 4; ++i_) {                                               \
      const int c_ = i_ * 256 + tid;                                               \
      const int row_ = c_ & 127, kg_ = c_ >> 7;                                    \
      gload_lds16(Bb + (size_t)row_ * 1024 + k0_ + kg_ * 8, &Bs[buf][c_ * 8]);     \
    }                                                                              \
  }

#define COMPUTE(cur)                                                                          \
  {                                                                                           \
    _Pragma("unroll")                                                                         \
    for (int ks = 0; ks < 2; ++ks) {                                                          \
      bf16x8 af[4], bfr[4];                                                                   \
      _Pragma("unroll")                                                                       \
      for (int m = 0; m < 4; ++m)                                                             \
        af[m] = *reinterpret_cast<const bf16x8*>(                                             \
            &As[cur][((ks * 4 + gr) * 128 + wr * 64 + m * 16 + li) * 8]);                     \
      _Pragma("unroll")                                                                       \
      for (int n = 0; n < 4; ++n)                                                             \
        bfr[n] = *reinterpret_cast<const bf16x8*>(                                            \
            &Bs[cur][((ks * 4 + gr) * 128 + wc * 64 + n * 16 + li) * 8]);                     \
      __builtin_amdgcn_s_setprio(1);                                                          \
      _Pragma("unroll")                                                                       \
      for (int m = 0; m < 4; ++m)                                                             \
        _Pragma("unroll")                                                                     \
        for (int n = 0; n < 4; ++n)                                                           \
          acc[m][n] = MFMA16(af[m], bfr[n], acc[m][n]);                                       \
      __builtin_amdgcn_s_setprio(0);                                                          \
    }                                                                                         \
  }

  STAGE(0, 0);
  STAGE(1, 1);

  for (int t = 0; t < 15; ++t) {
    const int cur = t & 1;
    asm volatile("s_waitcnt vmcnt(8)" ::: "memory");  // tile t landed; t+1 in flight
    __builtin_amdgcn_s_barrier();
    __builtin_amdgcn_sched_barrier(0);
    COMPUTE(cur);
    asm volatile("s_waitcnt lgkmcnt(0)" ::: "memory");
    __builtin_amdgcn_s_barrier();  // all waves done reading buf[cur]
    __builtin_amdgcn_sched_barrier(0);
    if (t < 14) STAGE(t + 2, cur);
  }
  // peeled last tile (t=15, cur=1)
  asm volatile("s_waitcnt vmcnt(0)" ::: "memory");
  __builtin_amdgcn_s_barrier();
  __builtin_amdgcn_sched_barrier(0);
  COMPUTE(1);
#undef STAGE
#undef COMPUTE

#pragma unroll
  for (int m = 0; m < 4; ++m)
#pragma unroll
    for (int n = 0; n < 4; ++n) {
      const int col = n0 + wc * 64 + n * 16 + li;
      const float bv_ = bias[col];
#pragma unroll
      for (int r = 0; r < 4; ++r) {
        const int row = m0 + wr * 64 + m * 16 + gr * 4 + r;
        C[(size_t)row * 1024 + col] = (bf16_t)((acc[m][n][r] + bv_) * sc);
      }
    }
}

// ---------------------------------------------------------------- summed bias bands
// 8192 blocks = (bh, qt, jt). Computes Dq = q·pk^T and Dk = k·pq^T over the 128-wide
// d-window (base wb = i0-j0+448), gathers diagonal SUM c2p(ii,jj)+p2c(ii,jj) and emits
// fragment-ordered bf16x4: slot ((bh*8+qt)*8+jt)*16 + wv*4 + n, lane l, elems r.
__global__ __launch_bounds__(256) void bias_sum(
    const bf16_t* __restrict__ qbuf, const bf16_t* __restrict__ kbuf,
    const bf16_t* __restrict__ pkb, const bf16_t* __restrict__ pqb,
    bf16_t* __restrict__ SBf) {
  const int bid0 = blockIdx.x;
  const int bid = (bid0 & 7) * 1024 + (bid0 >> 3);  // XCD chunks
  const int bh = bid >> 6;
  const int qt = (bid >> 3) & 7;
  const int jt = bid & 7;
  const int b = bh >> 4, h = bh & 15;
  const int i0 = qt * 64, j0 = jt * 64;
  const int wb = i0 - j0 + 448;  // window base in [0, 896]

  const bf16_t* Qg = qbuf + (size_t)(b * 512 + i0) * 1024 + h * 64;
  const bf16_t* Kg = kbuf + (size_t)(b * 512 + j0) * 1024 + h * 64;
  const bf16_t* PKg = pkb + (size_t)wb * 1024 + h * 64;
  const bf16_t* PQg = pqb + (size_t)wb * 1024 + h * 64;

  __shared__ bf16_t Qst[4096], Kst[4096];    // [64][64] kchunk layout
  __shared__ bf16_t PKst[8192], PQst[8192];  // [128][64] kchunk layout
  __shared__ bf16_t Dl[64 * 130];            // time-shared Dq then Dk

  const int tid = threadIdx.x;
#pragma unroll
  for (int i = 0; i < 2; ++i) {
    int c = tid + i * 256, s = c ^ ((c >> 3) & 7);
    gload_lds16(Qg + (size_t)(s >> 3) * 1024 + (s & 7) * 8, Qst + c * 8);
    gload_lds16(Kg + (size_t)(s >> 3) * 1024 + (s & 7) * 8, Kst + c * 8);
  }
#pragma unroll
  for (int i = 0; i < 4; ++i) {
    int c = tid + i * 256, s = c ^ ((c >> 3) & 7);
    gload_lds16(PKg + (size_t)(s >> 3) * 1024 + (s & 7) * 8, PKst + c * 8);
    gload_lds16(PQg + (size_t)(s >> 3) * 1024 + (s & 7) * 8, PQst + c * 8);
  }
  __syncthreads();

  const int l = tid & 63, wv = tid >> 6;
  const int li = l & 15, gr = l >> 4;
  float tmp[4][4];

  // ---- phase 1: Dq[q-row][pk-col], wave wv covers cols [wv*32, wv*32+32)
#pragma unroll
  for (int cgi = 0; cgi < 2; ++cgi) {
    const int cg = wv * 2 + cgi;
    bf16x8 pf0 = *reinterpret_cast<const bf16x8*>(PKst + kchunk(cg * 16 + li, gr) * 8);
    bf16x8 pf1 = *reinterpret_cast<const bf16x8*>(PKst + kchunk(cg * 16 + li, 4 + gr) * 8);
#pragma unroll
    for (int mg = 0; mg < 4; ++mg) {
      bf16x8 a0 = *reinterpret_cast<const bf16x8*>(Qst + kchunk(mg * 16 + li, gr) * 8);
      bf16x8 a1 = *reinterpret_cast<const bf16x8*>(Qst + kchunk(mg * 16 + li, 4 + gr) * 8);
      f32x4 d = {};
      d = MFMA16(a0, pf0, d);
      d = MFMA16(a1, pf1, d);
#pragma unroll
      for (int r = 0; r < 4; ++r)
        Dl[(mg * 16 + gr * 4 + r) * 130 + cg * 16 + li] = (bf16_t)d[r];
    }
  }
  __syncthreads();
  // gather c2p: (ii = wv*16+gr*4+r, jj = n*16+li) -> Dq[ii][ii-jj+63]
#pragma unroll
  for (int n = 0; n < 4; ++n)
#pragma unroll
    for (int r = 0; r < 4; ++r) {
      const int ii = wv * 16 + gr * 4 + r;
      tmp[n][r] = (float)Dl[ii * 130 + (ii - (n * 16 + li) + 63)];
    }
  __syncthreads();  // protect Dl before overwrite

  // ---- phase 2: Dk[k-row][pq-col]
#pragma unroll
  for (int cgi = 0; cgi < 2; ++cgi) {
    const int cg = wv * 2 + cgi;
    bf16x8 pf0 = *reinterpret_cast<const bf16x8*>(PQst + kchunk(cg * 16 + li, gr) * 8);
    bf16x8 pf1 = *reinterpret_cast<const bf16x8*>(PQst + kchunk(cg * 16 + li, 4 + gr) * 8);
#pragma unroll
    for (int mg = 0; mg < 4; ++mg) {
      bf16x8 a0 = *reinterpret_cast<const bf16x8*>(Kst + kchunk(mg * 16 + li, gr) * 8);
      bf16x8 a1 = *reinterpret_cast<const bf16x8*>(Kst + kchunk(mg * 16 + li, 4 + gr) * 8);
      f32x4 d = {};
      d = MFMA16(a0, pf0, d);
      d = MFMA16(a1, pf1, d);
#pragma unroll
      for (int r = 0; r < 4; ++r)
        Dl[(mg * 16 + gr * 4 + r) * 130 + cg * 16 + li] = (bf16_t)d[r];
    }
  }
  __syncthreads();
  // gather p2c + emit sum: p2c(ii,jj) = Dk[jj][ii-jj+63]
  bf16_t* outb = SBf + (((size_t)(bh * 8 + qt) * 8 + jt) * 16) * 256 + wv * 1024 + l * 4;
#pragma unroll
  for (int n = 0; n < 4; ++n) {
    bf16x4 ov;
#pragma unroll
    for (int r = 0; r < 4; ++r) {
      const int ii = wv * 16 + gr * 4 + r;
      const int jj = n * 16 + li;
      ov[r] = (bf16_t)(tmp[n][r] + (float)Dl[jj * 130 + (ii - jj + 63)]);
    }
    *reinterpret_cast<bf16x4*>(outb + n * 256) = ov;
  }
}

// ---------------------------------------------------------------- fused attention
// 1024 blocks (XCD-swizzled); 4 waves, wave owns 16 query rows; bias from SBf regs.
__global__ __launch_bounds__(256) void attn_fused(
    const bf16_t* __restrict__ qb, const bf16_t* __restrict__ kb,
    const bf16_t* __restrict__ vb, const bf16_t* __restrict__ SBf,
    float* __restrict__ out) {
  const int bid0 = blockIdx.x;
  const int bid = (bid0 & 7) * 128 + (bid0 >> 3);  // XCD-contiguous (b,h)
  const int qt = bid & 7;
  const int h = (bid >> 3) & 15;
  const int b = bid >> 7;
  const int i0 = qt * 64;
  const int tid = threadIdx.x;
  const int l = tid & 63;
  const int wv = tid >> 6;
  const int li = l & 15, gr = l >> 4;

  __shared__ bf16_t Kt[2][4096];   // [j][64] chunk-swizzled, double-buffered
  __shared__ bf16_t VT[4096];      // transposed V, chunk-swizzled
  __shared__ bf16_t Pl[4][1024];   // per-wave P A-frags, chunk-swizzled

  const int iq = i0 + wv * 16 + li;
  const bf16_t* qptr = qb + (size_t)(b * 512 + iq) * 1024 + h * 64 + gr * 8;
  const bf16x8 aq0 = *reinterpret_cast<const bf16x8*>(qptr);
  const bf16x8 aq1 = *reinterpret_cast<const bf16x8*>(qptr + 32);

  const bf16_t* kbase = kb + (size_t)(b * 512) * 1024 + h * 64;
  const bf16_t* vbase = vb + (size_t)(b * 512) * 1024 + h * 64;
  // bias fragment base for (bh,qt,wv,lane): + jt*4096 + n*256 per fragment
  const bf16_t* sbbase = SBf + (size_t)((b * 16 + h) * 8 + qt) * 32768 + wv * 1024 + l * 4;

  f32x4 acc[4] = {};
  float lsum[4] = {0.f, 0.f, 0.f, 0.f};
  bf16x8 vreg[2][2];
  bf16x4 sbr[2][4];

  // prologue: stage K(0), load V(0) regs, load bias frags (jt=0)
  {
    const int cl0 = tid, cl1 = tid + 256;
    int s0 = cl0 ^ ((cl0 >> 3) & 7), s1 = cl1 ^ ((cl1 >> 3) & 7);
    gload_lds16(kbase + (size_t)(s0 >> 3) * 1024 + (s0 & 7) * 8, Kt[0] + cl0 * 8);
    gload_lds16(kbase + (size_t)(s1 >> 3) * 1024 + (s1 & 7) * 8, Kt[0] + cl1 * 8);
    vreg[0][0] = *reinterpret_cast<const bf16x8*>(vbase + (size_t)(tid >> 3) * 1024 + (tid & 7) * 8);
    vreg[0][1] = *reinterpret_cast<const bf16x8*>(vbase + (size_t)(32 + (tid >> 3)) * 1024 + (tid & 7) * 8);
#pragma unroll
    for (int n = 0; n < 4; ++n)
      sbr[0][n] = *reinterpret_cast<const bf16x4*>(sbbase + n * 256);
  }

#pragma unroll
  for (int jt = 0; jt < 8; ++jt) {
    const int cur = jt & 1;
    const bf16_t* KtC = Kt[cur];
    __syncthreads();  // vmcnt(0) drain: K/V/bias of cur arrived

    if (jt < 7) {  // prefetch next tile (stays in flight across mid barrier)
      const int j0n = (jt + 1) * 64;
      const int cl0 = tid, cl1 = tid + 256;
      int s0 = cl0 ^ ((cl0 >> 3) & 7), s1 = cl1 ^ ((cl1 >> 3) & 7);
      bf16_t* KtN = Kt[cur ^ 1];
      gload_lds16(kbase + (size_t)(j0n + (s0 >> 3)) * 1024 + (s0 & 7) * 8, KtN + cl0 * 8);
      gload_lds16(kbase + (size_t)(j0n + (s1 >> 3)) * 1024 + (s1 & 7) * 8, KtN + cl1 * 8);
      vreg[cur ^ 1][0] = *reinterpret_cast<const bf16x8*>(vbase + (size_t)(j0n + (tid >> 3)) * 1024 + (tid & 7) * 8);
      vreg[cur ^ 1][1] = *reinterpret_cast<const bf16x8*>(vbase + (size_t)(j0n + 32 + (tid >> 3)) * 1024 + (tid & 7) * 8);
#pragma unroll
      for (int n = 0; n < 4; ++n)
        sbr[cur ^ 1][n] = *reinterpret_cast<const bf16x4*>(sbbase + (jt + 1) * 4096 + n * 256);
    }

    // fill VT (transposed, swizzled) from V regs of current tile
#pragma unroll
    for (int cc = 0; cc < 2; ++cc) {
      const int j = cc * 32 + (tid >> 3);
      const int w0 = (tid & 7) * 8;
      bf16x8 vv = vreg[cur][cc];
#pragma unroll
      for (int e = 0; e < 8; ++e) {
        int ch = (j >> 3) * 64 + w0 + e;
        ch ^= ((ch >> 3) & 7);
        VT[ch * 8 + (j & 7)] = vv[e];
      }
    }

    __builtin_amdgcn_s_setprio(1);
    f32x4 sfr[4];
#pragma unroll
    for (int n = 0; n < 4; ++n) {
      const int j_ = n * 16 + li;
      bf16x8 b0 = *reinterpret_cast<const bf16x8*>(KtC + kchunk(j_, gr) * 8);
      bf16x8 b1 = *reinterpret_cast<const bf16x8*>(KtC + kchunk(j_, 4 + gr) * 8);
      f32x4 t = {};
      t = MFMA16(aq0, b0, t);
      t = MFMA16(aq1, b1, t);
      sfr[n] = t;
    }
    __builtin_amdgcn_s_setprio(0);

    // softmax (fixed max): p = exp2(s - MCONST)
#pragma unroll
    for (int n = 0; n < 4; ++n) {
#pragma unroll
      for (int r = 0; r < 4; ++r) {
        const float s = sfr[n][r] + (float)sbr[cur][n][r] - MCONST;
        const float pe = __builtin_amdgcn_exp2f(s);
        lsum[r] += pe;
        int ch = (n * 2 + (li >> 3)) * 16 + gr * 4 + r;
        ch ^= ((ch >> 3) & 7);
        Pl[wv][ch * 8 + (li & 7)] = (bf16_t)pe;
      }
    }

    // mid barrier: LDS drain only (keeps K/V/bias prefetch in flight)
    asm volatile("s_waitcnt lgkmcnt(0)" ::: "memory");
    __builtin_amdgcn_s_barrier();
    __builtin_amdgcn_sched_barrier(0);

    __builtin_amdgcn_s_setprio(1);
#pragma unroll
    for (int ks = 0; ks < 2; ++ks) {
      int chA = (ks * 4 + gr) * 16 + li;
      chA ^= ((chA >> 3) & 7);
      bf16x8 ap = *reinterpret_cast<const bf16x8*>(Pl[wv] + chA * 8);
#pragma unroll
      for (int n2 = 0; n2 < 4; ++n2) {
        int chB = (ks * 4 + gr) * 64 + n2 * 16 + li;
        chB ^= ((chB >> 3) & 7);
        bf16x8 bvf = *reinterpret_cast<const bf16x8*>(VT + chB * 8);
        acc[n2] = MFMA16(ap, bvf, acc[n2]);
      }
    }
    __builtin_amdgcn_s_setprio(0);
  }

  // reduce lsum across the 16 li lanes, then normalize + store
#pragma unroll
  for (int mm = 1; mm < 16; mm <<= 1)
#pragma unroll
    for (int r = 0; r < 4; ++r)
      lsum[r] += __shfl_xor(lsum[r], mm, 64);
  float invl[4];
#pragma unroll
  for (int r = 0; r < 4; ++r) invl[r] = 1.0f / lsum[r];

#pragma unroll
  for (int n2 = 0; n2 < 4; ++n2)
#pragma unroll
    for (int r = 0; r < 4; ++r) {
      const int i = i0 + wv * 16 + gr * 4 + r;
      const int wcol = n2 * 16 + li;
      out[(size_t)(b * 512 + i) * 1024 + h * 64 + wcol] = acc[n2][r] * invl[r];
    }
}

// ---------------------------------------------------------------- launch
extern "C" void kernel_launch(void* const* d_in, const int* in_sizes, int n_in,
                              void* d_out, int out_size, void* d_ws, size_t ws_size,
                              hipStream_t stream) {
  (void)in_sizes; (void)n_in; (void)out_size; (void)ws_size;
  const float* x   = (const float*)d_in[0];
  const float* rel = (const float*)d_in[1];
  const float* Wq  = (const float*)d_in[2];
  const float* bq  = (const float*)d_in[3];
  const float* Wk  = (const float*)d_in[4];
  const float* bk  = (const float*)d_in[5];
  const float* Wv  = (const float*)d_in[6];
  const float* bv  = (const float*)d_in[7];
  float* out = (float*)d_out;

  bf16_t* ws  = (bf16_t*)d_ws;
  bf16_t* xb  = ws;                 // 4 M elems
  bf16_t* wqb = xb + 4194304;       // 1 M each
  bf16_t* wkb = wqb + 1048576;
  bf16_t* wvb = wkb + 1048576;
  bf16_t* reb = wvb + 1048576;
  bf16_t* qbuf = reb + 1048576;     // 4 M each
  bf16_t* kbuf = qbuf + 4194304;
  bf16_t* vbuf = kbuf + 4194304;
  bf16_t* pkb = vbuf + 4194304;     // 1 M each
  bf16_t* pqb = pkb + 1048576;
  bf16_t* SBf = pqb + 1048576;      // 33.55 M elems (total ws ~111 MB)

  cvt_all<<<8192, 256, 0, stream>>>(x, rel, Wq, Wk, Wv, ws);
  gemm_all<<<896, 256, 0, stream>>>(xb, reb, wqb, wkb, wvb,
                                    bq, bk, bv, qbuf, kbuf, vbuf, pkb, pqb);
  bias_sum<<<8192, 256, 0, stream>>>(qbuf, kbuf, pkb, pqb, SBf);
  attn_fused<<<1024, 256, 0, stream>>>(qbuf, kbuf, vbuf, SBf, out);
}

// Round 6
// 147.392 us; speedup vs baseline: 1.1895x; 1.1895x over previous
//
#include <hip/hip_runtime.h>

// FTDisentangledMHA: B=8, S=512, D=1024, H=16, Wd=64, MAX_REL=512 (span==S)
// scores(i,j) = scale*(q_i.k_j + q_i.pk[i-j+511] + k_j.pq[i-j+511]); no clip, mask all-true.
// q,pq pre-scaled by scale*log2e; softmax = exp2 with fixed max M=3.
// R6: projection GEMMs -> ONE 256^2-tile 8-wave kernel (224 blocks) with the proven
//     8-phase interleave: per phase {ds_read frags | stage 1 unit | barrier | lgkm0 |
//     16 MFMA | barrier}, counted vmcnt(2) at phases 2/4 only. bias_sum/attn unchanged.

typedef __bf16 bf16_t;
typedef __bf16 bf16x8 __attribute__((ext_vector_type(8)));
typedef __bf16 bf16x4 __attribute__((ext_vector_type(4)));
typedef float  f32x4  __attribute__((ext_vector_type(4)));

#define MFMA16(a, b, c) __builtin_amdgcn_mfma_f32_16x16x32_bf16((a), (b), (c), 0, 0, 0)
#define S2SCALE 0.10411754f   // (1/sqrt(192)) * log2(e)
#define MCONST  4.3280851f    // 3 * log2(e)

__device__ __forceinline__ void gload_lds16(const bf16_t* g, bf16_t* lds) {
  __builtin_amdgcn_global_load_lds(
      (const __attribute__((address_space(1))) void*)g,
      (__attribute__((address_space(3))) void*)lds, 16, 0, 0);
}

// chunk swizzle for row-major [rows][64] bf16 tiles staged as 16B chunks
__device__ __forceinline__ int kchunk(int row, int kg) {
  return row * 8 + (kg ^ (row & 7));
}

// ---------------------------------------------------------------- fp32 -> bf16 (all 5 arrays)
__global__ __launch_bounds__(256) void cvt_all(
    const float* __restrict__ x, const float* __restrict__ rel,
    const float* __restrict__ wq, const float* __restrict__ wk, const float* __restrict__ wv,
    bf16_t* __restrict__ out) {
  const size_t i = ((size_t)blockIdx.x * 256 + threadIdx.x) * 4;
  const float* src; size_t off;
  if (i < 4194304) { src = x; off = i; }
  else {
    size_t j = i - 4194304; int sel = (int)(j >> 20); off = j & 1048575;
    src = sel == 0 ? wq : sel == 1 ? wk : sel == 2 ? wv : rel;
  }
  float4 v = *reinterpret_cast<const float4*>(src + off);
  bf16x4 o;
  o[0] = (bf16_t)v.x; o[1] = (bf16_t)v.y; o[2] = (bf16_t)v.z; o[3] = (bf16_t)v.w;
  *reinterpret_cast<bf16x4*>(out + i) = o;
}

// ------------------------------------------------- 256^2-tile 8-phase projection GEMM
// Tile: BM=BN=256, BK=32 (K-tile); iteration = 2 K-tiles (buf0 even, buf1 odd), 4 phases.
// 8 waves = 2(M)x4(N); per-wave C = 128x64 = acc[8][4]. LDS 64KB: A/B tiles 256x32
// as [row(256)][kg(4)] 16B chunks, swizzle kg^=(row&3).
__device__ __forceinline__ void stage_tile(const bf16_t* base, int T, bf16_t* lds, int tid) {
#pragma unroll
  for (int i = 0; i < 2; ++i) {
    const int c = tid + i * 512;
    const int row = c >> 2, kg = (c & 3) ^ (row & 3);
    gload_lds16(base + (size_t)row * 1024 + T * 32 + kg * 8, lds + c * 8);
  }
}

#define VMW2 asm volatile("s_waitcnt vmcnt(2)" ::: "memory")
#define VMW0 asm volatile("s_waitcnt vmcnt(0)" ::: "memory")
#define NOPS ((void)0)

#define PH_BODY(AB, BB, FH, READB, STAGE_STMT, WAIT_STMT)                               \
  {                                                                                     \
    if (READB) {                                                                        \
      _Pragma("unroll") for (int n_ = 0; n_ < 4; ++n_)                                  \
        bfr[n_] = *reinterpret_cast<const bf16x8*>(                                     \
            (BB) + (((wn * 64 + n_ * 16 + li) * 4 + (gr ^ (li & 3))) * 8));             \
    }                                                                                   \
    bf16x8 af_[4];                                                                      \
    _Pragma("unroll") for (int a_ = 0; a_ < 4; ++a_)                                    \
      af_[a_] = *reinterpret_cast<const bf16x8*>(                                       \
          (AB) + (((wm * 128 + ((FH) * 4 + a_) * 16 + li) * 4 + (gr ^ (li & 3))) * 8)); \
    STAGE_STMT;                                                                         \
    __builtin_amdgcn_s_barrier();                                                       \
    asm volatile("s_waitcnt lgkmcnt(0)" ::: "memory");                                  \
    __builtin_amdgcn_sched_barrier(0);                                                  \
    __builtin_amdgcn_s_setprio(1);                                                      \
    _Pragma("unroll") for (int a_ = 0; a_ < 4; ++a_)                                    \
      _Pragma("unroll") for (int n_ = 0; n_ < 4; ++n_)                                  \
        acc[(FH) * 4 + a_][n_] = MFMA16(af_[a_], bfr[n_], acc[(FH) * 4 + a_][n_]);      \
    __builtin_amdgcn_s_setprio(0);                                                      \
    WAIT_STMT;                                                                          \
    __builtin_amdgcn_s_barrier();                                                       \
    __builtin_amdgcn_sched_barrier(0);                                                  \
  }

__global__ __launch_bounds__(512, 2) void gemm_qkv(
    const bf16_t* __restrict__ xb, const bf16_t* __restrict__ reb,
    const bf16_t* __restrict__ wqb, const bf16_t* __restrict__ wkb, const bf16_t* __restrict__ wvb,
    const float* __restrict__ bq, const float* __restrict__ bk, const float* __restrict__ bv,
    bf16_t* __restrict__ qo, bf16_t* __restrict__ ko, bf16_t* __restrict__ vo,
    bf16_t* __restrict__ pko, bf16_t* __restrict__ pqo) {
  __shared__ bf16_t Abuf[2][8192];
  __shared__ bf16_t Bbuf[2][8192];

  const int bid0 = blockIdx.x;
  const int bid = (bid0 & 7) * 28 + (bid0 >> 3);  // 224 = 8*28, bijective XCD chunks
  const int tid = threadIdx.x;
  const int wave = tid >> 6;
  const int wm = wave >> 2, wn = wave & 3;
  const int l = tid & 63, li = l & 15, gr = l >> 4;

  const bf16_t* Abase; const bf16_t* Bbase; const float* bias; float sc;
  bf16_t* Cout; int row0, col0;
  if (bid < 192) {  // main: x (4096) x [Wq|Wk|Wv] (3072)
    const int bx = bid / 12, by = bid % 12;
    Abase = xb + (size_t)bx * 262144; row0 = bx * 256;
    const int wsel = by >> 2;
    Bbase = (wsel == 0 ? wqb : wsel == 1 ? wkb : wvb) + (size_t)(by & 3) * 262144;
    bias = wsel == 0 ? bq : wsel == 1 ? bk : bv;
    sc = wsel == 0 ? S2SCALE : 1.f;
    Cout = wsel == 0 ? qo : wsel == 1 ? ko : vo;
    col0 = (by & 3) * 256;
  } else {  // pos: re (1024) x [Wk|Wq] (2048)
    const int p = bid - 192;
    const int bx = p >> 3, by = p & 7;
    Abase = reb + (size_t)bx * 262144; row0 = bx * 256;
    const int wsel = by >> 2;
    Bbase = (wsel == 0 ? wkb : wqb) + (size_t)(by & 3) * 262144;
    bias = wsel == 0 ? bk : bq;
    sc = wsel == 0 ? 1.f : S2SCALE;
    Cout = wsel == 0 ? pko : pqo;
    col0 = (by & 3) * 256;
  }

  f32x4 acc[8][4] = {};
  bf16x8 bfr[4];

  // prologue: A(0),B(0) -> buf0; B(1) -> buf1. Wait the first 4 (A0,B0), leave B1 flying.
  stage_tile(Abase, 0, Abuf[0], tid);
  stage_tile(Bbase, 0, Bbuf[0], tid);
  stage_tile(Bbase, 1, Bbuf[1], tid);
  VMW2;
  __builtin_amdgcn_s_barrier();
  __builtin_amdgcn_sched_barrier(0);

  // steady: iter t covers K-tiles 2t (buf0) and 2t+1 (buf1).
  // ph1 stages A(2t+1)->buf1 ; ph2: B(2t+2)->buf0 + vmcnt(2) ; ph3: A(2t+2)->buf0 ;
  // ph4: B(2t+3)->buf1 + vmcnt(2).  Ledger: vmcnt(2) at ph2 confirms {B(2t+1),A(2t+1)},
  // at ph4 confirms {B(2t+2),A(2t+2)} — exactly what the next phase/iter reads.
  for (int t = 0; t < 15; ++t) {
    const int T0 = 2 * t;
    PH_BODY(Abuf[0], Bbuf[0], 0, true,  stage_tile(Abase, T0 + 1, Abuf[1], tid), NOPS);
    PH_BODY(Abuf[0], Bbuf[0], 1, false, stage_tile(Bbase, T0 + 2, Bbuf[0], tid), VMW2);
    PH_BODY(Abuf[1], Bbuf[1], 0, true,  stage_tile(Abase, T0 + 2, Abuf[0], tid), NOPS);
    PH_BODY(Abuf[1], Bbuf[1], 1, false, stage_tile(Bbase, T0 + 3, Bbuf[1], tid), VMW2);
  }
  // peeled t=15 (tiles 30,31): only A(31) still to stage.
  PH_BODY(Abuf[0], Bbuf[0], 0, true,  stage_tile(Abase, 31, Abuf[1], tid), NOPS);
  PH_BODY(Abuf[0], Bbuf[0], 1, false, NOPS, VMW0);
  PH_BODY(Abuf[1], Bbuf[1], 0, true,  NOPS, NOPS);
  PH_BODY(Abuf[1], Bbuf[1], 1, false, NOPS, NOPS);

  // epilogue
#pragma unroll
  for (int a = 0; a < 8; ++a)
#pragma unroll
    for (int n = 0; n < 4; ++n) {
      const int col = col0 + wn * 64 + n * 16 + li;
      const float bv_ = bias[col];
#pragma unroll
      for (int r = 0; r < 4; ++r) {
        const int row = row0 + wm * 128 + a * 16 + gr * 4 + r;
        Cout[(size_t)row * 1024 + col] = (bf16_t)((acc[a][n][r] + bv_) * sc);
      }
    }
}

// ---------------------------------------------------------------- summed bias bands
// 8192 blocks = (bh, qt, jt). Computes Dq = q·pk^T and Dk = k·pq^T over the 128-wide
// d-window (base wb = i0-j0+448), gathers diagonal SUM c2p(ii,jj)+p2c(ii,jj) and emits
// fragment-ordered bf16x4: slot ((bh*8+qt)*8+jt)*16 + wv*4 + n, lane l, elems r.
__global__ __launch_bounds__(256) void bias_sum(
    const bf16_t* __restrict__ qbuf, const bf16_t* __restrict__ kbuf,
    const bf16_t* __restrict__ pkb, const bf16_t* __restrict__ pqb,
    bf16_t* __restrict__ SBf) {
  const int bid0 = blockIdx.x;
  const int bid = (bid0 & 7) * 1024 + (bid0 >> 3);  // XCD chunks
  const int bh = bid >> 6;
  const int qt = (bid >> 3) & 7;
  const int jt = bid & 7;
  const int b = bh >> 4, h = bh & 15;
  const int i0 = qt * 64, j0 = jt * 64;
  const int wb = i0 - j0 + 448;  // window base in [0, 896]

  const bf16_t* Qg = qbuf + (size_t)(b * 512 + i0) * 1024 + h * 64;
  const bf16_t* Kg = kbuf + (size_t)(b * 512 + j0) * 1024 + h * 64;
  const bf16_t* PKg = pkb + (size_t)wb * 1024 + h * 64;
  const bf16_t* PQg = pqb + (size_t)wb * 1024 + h * 64;

  __shared__ bf16_t Qst[4096], Kst[4096];    // [64][64] kchunk layout
  __shared__ bf16_t PKst[8192], PQst[8192];  // [128][64] kchunk layout
  __shared__ bf16_t Dl[64 * 130];            // time-shared Dq then Dk

  const int tid = threadIdx.x;
#pragma unroll
  for (int i = 0; i < 2; ++i) {
    int c = tid + i * 256, s = c ^ ((c >> 3) & 7);
    gload_lds16(Qg + (size_t)(s >> 3) * 1024 + (s & 7) * 8, Qst + c * 8);
    gload_lds16(Kg + (size_t)(s >> 3) * 1024 + (s & 7) * 8, Kst + c * 8);
  }
#pragma unroll
  for (int i = 0; i < 4; ++i) {
    int c = tid + i * 256, s = c ^ ((c >> 3) & 7);
    gload_lds16(PKg + (size_t)(s >> 3) * 1024 + (s & 7) * 8, PKst + c * 8);
    gload_lds16(PQg + (size_t)(s >> 3) * 1024 + (s & 7) * 8, PQst + c * 8);
  }
  __syncthreads();

  const int l = tid & 63, wv = tid >> 6;
  const int li = l & 15, gr = l >> 4;
  float tmp[4][4];

  // ---- phase 1: Dq[q-row][pk-col], wave wv covers cols [wv*32, wv*32+32)
#pragma unroll
  for (int cgi = 0; cgi < 2; ++cgi) {
    const int cg = wv * 2 + cgi;
    bf16x8 pf0 = *reinterpret_cast<const bf16x8*>(PKst + kchunk(cg * 16 + li, gr) * 8);
    bf16x8 pf1 = *reinterpret_cast<const bf16x8*>(PKst + kchunk(cg * 16 + li, 4 + gr) * 8);
#pragma unroll
    for (int mg = 0; mg < 4; ++mg) {
      bf16x8 a0 = *reinterpret_cast<const bf16x8*>(Qst + kchunk(mg * 16 + li, gr) * 8);
      bf16x8 a1 = *reinterpret_cast<const bf16x8*>(Qst + kchunk(mg * 16 + li, 4 + gr) * 8);
      f32x4 d = {};
      d = MFMA16(a0, pf0, d);
      d = MFMA16(a1, pf1, d);
#pragma unroll
      for (int r = 0; r < 4; ++r)
        Dl[(mg * 16 + gr * 4 + r) * 130 + cg * 16 + li] = (bf16_t)d[r];
    }
  }
  __syncthreads();
  // gather c2p: (ii = wv*16+gr*4+r, jj = n*16+li) -> Dq[ii][ii-jj+63]
#pragma unroll
  for (int n = 0; n < 4; ++n)
#pragma unroll
    for (int r = 0; r < 4; ++r) {
      const int ii = wv * 16 + gr * 4 + r;
      tmp[n][r] = (float)Dl[ii * 130 + (ii - (n * 16 + li) + 63)];
    }
  __syncthreads();  // protect Dl before overwrite

  // ---- phase 2: Dk[k-row][pq-col]
#pragma unroll
  for (int cgi = 0; cgi < 2; ++cgi) {
    const int cg = wv * 2 + cgi;
    bf16x8 pf0 = *reinterpret_cast<const bf16x8*>(PQst + kchunk(cg * 16 + li, gr) * 8);
    bf16x8 pf1 = *reinterpret_cast<const bf16x8*>(PQst + kchunk(cg * 16 + li, 4 + gr) * 8);
#pragma unroll
    for (int mg = 0; mg < 4; ++mg) {
      bf16x8 a0 = *reinterpret_cast<const bf16x8*>(Kst + kchunk(mg * 16 + li, gr) * 8);
      bf16x8 a1 = *reinterpret_cast<const bf16x8*>(Kst + kchunk(mg * 16 + li, 4 + gr) * 8);
      f32x4 d = {};
      d = MFMA16(a0, pf0, d);
      d = MFMA16(a1, pf1, d);
#pragma unroll
      for (int r = 0; r < 4; ++r)
        Dl[(mg * 16 + gr * 4 + r) * 130 + cg * 16 + li] = (bf16_t)d[r];
    }
  }
  __syncthreads();
  // gather p2c + emit sum: p2c(ii,jj) = Dk[jj][ii-jj+63]
  bf16_t* outb = SBf + (((size_t)(bh * 8 + qt) * 8 + jt) * 16) * 256 + wv * 1024 + l * 4;
#pragma unroll
  for (int n = 0; n < 4; ++n) {
    bf16x4 ov;
#pragma unroll
    for (int r = 0; r < 4; ++r) {
      const int ii = wv * 16 + gr * 4 + r;
      const int jj = n * 16 + li;
      ov[r] = (bf16_t)(tmp[n][r] + (float)Dl[jj * 130 + (ii - jj + 63)]);
    }
    *reinterpret_cast<bf16x4*>(outb + n * 256) = ov;
  }
}

// ---------------------------------------------------------------- fused attention
// 1024 blocks (XCD-swizzled); 4 waves, wave owns 16 query rows; bias from SBf regs.
__global__ __launch_bounds__(256) void attn_fused(
    const bf16_t* __restrict__ qb, const bf16_t* __restrict__ kb,
    const bf16_t* __restrict__ vb, const bf16_t* __restrict__ SBf,
    float* __restrict__ out) {
  const int bid0 = blockIdx.x;
  const int bid = (bid0 & 7) * 128 + (bid0 >> 3);  // XCD-contiguous (b,h)
  const int qt = bid & 7;
  const int h = (bid >> 3) & 15;
  const int b = bid >> 7;
  const int i0 = qt * 64;
  const int tid = threadIdx.x;
  const int l = tid & 63;
  const int wv = tid >> 6;
  const int li = l & 15, gr = l >> 4;

  __shared__ bf16_t Kt[2][4096];   // [j][64] chunk-swizzled, double-buffered
  __shared__ bf16_t VT[4096];      // transposed V, chunk-swizzled
  __shared__ bf16_t Pl[4][1024];   // per-wave P A-frags, chunk-swizzled

  const int iq = i0 + wv * 16 + li;
  const bf16_t* qptr = qb + (size_t)(b * 512 + iq) * 1024 + h * 64 + gr * 8;
  const bf16x8 aq0 = *reinterpret_cast<const bf16x8*>(qptr);
  const bf16x8 aq1 = *reinterpret_cast<const bf16x8*>(qptr + 32);

  const bf16_t* kbase = kb + (size_t)(b * 512) * 1024 + h * 64;
  const bf16_t* vbase = vb + (size_t)(b * 512) * 1024 + h * 64;
  // bias fragment base for (bh,qt,wv,lane): + jt*4096 + n*256 per fragment
  const bf16_t* sbbase = SBf + (size_t)((b * 16 + h) * 8 + qt) * 32768 + wv * 1024 + l * 4;

  f32x4 acc[4] = {};
  float lsum[4] = {0.f, 0.f, 0.f, 0.f};
  bf16x8 vreg[2][2];
  bf16x4 sbr[2][4];

  // prologue: stage K(0), load V(0) regs, load bias frags (jt=0)
  {
    const int cl0 = tid, cl1 = tid + 256;
    int s0 = cl0 ^ ((cl0 >> 3) & 7), s1 = cl1 ^ ((cl1 >> 3) & 7);
    gload_lds16(kbase + (size_t)(s0 >> 3) * 1024 + (s0 & 7) * 8, Kt[0] + cl0 * 8);
    gload_lds16(kbase + (size_t)(s1 >> 3) * 1024 + (s1 & 7) * 8, Kt[0] + cl1 * 8);
    vreg[0][0] = *reinterpret_cast<const bf16x8*>(vbase + (size_t)(tid >> 3) * 1024 + (tid & 7) * 8);
    vreg[0][1] = *reinterpret_cast<const bf16x8*>(vbase + (size_t)(32 + (tid >> 3)) * 1024 + (tid & 7) * 8);
#pragma unroll
    for (int n = 0; n < 4; ++n)
      sbr[0][n] = *reinterpret_cast<const bf16x4*>(sbbase + n * 256);
  }

#pragma unroll
  for (int jt = 0; jt < 8; ++jt) {
    const int cur = jt & 1;
    const bf16_t* KtC = Kt[cur];
    __syncthreads();  // vmcnt(0) drain: K/V/bias of cur arrived

    if (jt < 7) {  // prefetch next tile (stays in flight across mid barrier)
      const int j0n = (jt + 1) * 64;
      const int cl0 = tid, cl1 = tid + 256;
      int s0 = cl0 ^ ((cl0 >> 3) & 7), s1 = cl1 ^ ((cl1 >> 3) & 7);
      bf16_t* KtN = Kt[cur ^ 1];
      gload_lds16(kbase + (size_t)(j0n + (s0 >> 3)) * 1024 + (s0 & 7) * 8, KtN + cl0 * 8);
      gload_lds16(kbase + (size_t)(j0n + (s1 >> 3)) * 1024 + (s1 & 7) * 8, KtN + cl1 * 8);
      vreg[cur ^ 1][0] = *reinterpret_cast<const bf16x8*>(vbase + (size_t)(j0n + (tid >> 3)) * 1024 + (tid & 7) * 8);
      vreg[cur ^ 1][1] = *reinterpret_cast<const bf16x8*>(vbase + (size_t)(j0n + 32 + (tid >> 3)) * 1024 + (tid & 7) * 8);
#pragma unroll
      for (int n = 0; n < 4; ++n)
        sbr[cur ^ 1][n] = *reinterpret_cast<const bf16x4*>(sbbase + (jt + 1) * 4096 + n * 256);
    }

    // fill VT (transposed, swizzled) from V regs of current tile
#pragma unroll
    for (int cc = 0; cc < 2; ++cc) {
      const int j = cc * 32 + (tid >> 3);
      const int w0 = (tid & 7) * 8;
      bf16x8 vv = vreg[cur][cc];
#pragma unroll
      for (int e = 0; e < 8; ++e) {
        int ch = (j >> 3) * 64 + w0 + e;
        ch ^= ((ch >> 3) & 7);
        VT[ch * 8 + (j & 7)] = vv[e];
      }
    }

    __builtin_amdgcn_s_setprio(1);
    f32x4 sfr[4];
#pragma unroll
    for (int n = 0; n < 4; ++n) {
      const int j_ = n * 16 + li;
      bf16x8 b0 = *reinterpret_cast<const bf16x8*>(KtC + kchunk(j_, gr) * 8);
      bf16x8 b1 = *reinterpret_cast<const bf16x8*>(KtC + kchunk(j_, 4 + gr) * 8);
      f32x4 t = {};
      t = MFMA16(aq0, b0, t);
      t = MFMA16(aq1, b1, t);
      sfr[n] = t;
    }
    __builtin_amdgcn_s_setprio(0);

    // softmax (fixed max): p = exp2(s - MCONST)
#pragma unroll
    for (int n = 0; n < 4; ++n) {
#pragma unroll
      for (int r = 0; r < 4; ++r) {
        const float s = sfr[n][r] + (float)sbr[cur][n][r] - MCONST;
        const float pe = __builtin_amdgcn_exp2f(s);
        lsum[r] += pe;
        int ch = (n * 2 + (li >> 3)) * 16 + gr * 4 + r;
        ch ^= ((ch >> 3) & 7);
        Pl[wv][ch * 8 + (li & 7)] = (bf16_t)pe;
      }
    }

    // mid barrier: LDS drain only (keeps K/V/bias prefetch in flight)
    asm volatile("s_waitcnt lgkmcnt(0)" ::: "memory");
    __builtin_amdgcn_s_barrier();
    __builtin_amdgcn_sched_barrier(0);

    __builtin_amdgcn_s_setprio(1);
#pragma unroll
    for (int ks = 0; ks < 2; ++ks) {
      int chA = (ks * 4 + gr) * 16 + li;
      chA ^= ((chA >> 3) & 7);
      bf16x8 ap = *reinterpret_cast<const bf16x8*>(Pl[wv] + chA * 8);
#pragma unroll
      for (int n2 = 0; n2 < 4; ++n2) {
        int chB = (ks * 4 + gr) * 64 + n2 * 16 + li;
        chB ^= ((chB >> 3) & 7);
        bf16x8 bvf = *reinterpret_cast<const bf16x8*>(VT + chB * 8);
        acc[n2] = MFMA16(ap, bvf, acc[n2]);
      }
    }
    __builtin_amdgcn_s_setprio(0);
  }

  // reduce lsum across the 16 li lanes, then normalize + store
#pragma unroll
  for (int mm = 1; mm < 16; mm <<= 1)
#pragma unroll
    for (int r = 0; r < 4; ++r)
      lsum[r] += __shfl_xor(lsum[r], mm, 64);
  float invl[4];
#pragma unroll
  for (int r = 0; r < 4; ++r) invl[r] = 1.0f / lsum[r];

#pragma unroll
  for (int n2 = 0; n2 < 4; ++n2)
#pragma unroll
    for (int r = 0; r < 4; ++r) {
      const int i = i0 + wv * 16 + gr * 4 + r;
      const int wcol = n2 * 16 + li;
      out[(size_t)(b * 512 + i) * 1024 + h * 64 + wcol] = acc[n2][r] * invl[r];
    }
}

// ---------------------------------------------------------------- launch
extern "C" void kernel_launch(void* const* d_in, const int* in_sizes, int n_in,
                              void* d_out, int out_size, void* d_ws, size_t ws_size,
                              hipStream_t stream) {
  (void)in_sizes; (void)n_in; (void)out_size; (void)ws_size;
  const float* x   = (const float*)d_in[0];
  const float* rel = (const float*)d_in[1];
  const float* Wq  = (const float*)d_in[2];
  const float* bq  = (const float*)d_in[3];
  const float* Wk  = (const float*)d_in[4];
  const float* bk  = (const float*)d_in[5];
  const float* Wv  = (const float*)d_in[6];
  const float* bv  = (const float*)d_in[7];
  float* out = (float*)d_out;

  bf16_t* ws  = (bf16_t*)d_ws;
  bf16_t* xb  = ws;                 // 4 M elems
  bf16_t* wqb = xb + 4194304;       // 1 M each
  bf16_t* wkb = wqb + 1048576;
  bf16_t* wvb = wkb + 1048576;
  bf16_t* reb = wvb + 1048576;
  bf16_t* qbuf = reb + 1048576;     // 4 M each
  bf16_t* kbuf = qbuf + 4194304;
  bf16_t* vbuf = kbuf + 4194304;
  bf16_t* pkb = vbuf + 4194304;     // 1 M each
  bf16_t* pqb = pkb + 1048576;
  bf16_t* SBf = pqb + 1048576;      // 33.55 M elems (total ws ~111 MB)

  cvt_all<<<8192, 256, 0, stream>>>(x, rel, Wq, Wk, Wv, ws);
  gemm_qkv<<<224, 512, 0, stream>>>(xb, reb, wqb, wkb, wvb,
                                    bq, bk, bv, qbuf, kbuf, vbuf, pkb, pqb);
  bias_sum<<<8192, 256, 0, stream>>>(qbuf, kbuf, pkb, pqb, SBf);
  attn_fused<<<1024, 256, 0, stream>>>(qbuf, kbuf, vbuf, SBf, out);
}

// Round 7
// 114.868 us; speedup vs baseline: 1.5264x; 1.2831x over previous
//
#include <hip/hip_runtime.h>

// FTDisentangledMHA: B=8, S=512, D=1024, H=16, Wd=64, MAX_REL=512 (span==S)
// scores(i,j) = scale*(q_i.k_j + q_i.pk[d] + k_j.pq[d]), d = i-j+511 (never clipped).
// q,pq pre-scaled by scale*log2e; softmax = exp2 with fixed max M=3.
// R7: bias_sum + attn merged into attn_mega. Per block (bh, qt-pair): pk/pq staged as
// a ring of 64-row segments (each row staged once); per jt each wave computes its
// 16x80 c2p strip (q·pk^T) and p2c strip (k·pq^T) via MFMA, stores them [jj][ii] in
// LDS, and gathers both with conflict-free b64 reads straight into the QK^T fragments.

typedef __bf16 bf16_t;
typedef __bf16 bf16x8 __attribute__((ext_vector_type(8)));
typedef __bf16 bf16x4 __attribute__((ext_vector_type(4)));
typedef float  f32x4  __attribute__((ext_vector_type(4)));

#define MFMA16(a, b, c) __builtin_amdgcn_mfma_f32_16x16x32_bf16((a), (b), (c), 0, 0, 0)
#define S2SCALE 0.10411754f   // (1/sqrt(192)) * log2(e)
#define MCONST  4.3280851f    // 3 * log2(e)

__device__ __forceinline__ void gload_lds16(const bf16_t* g, bf16_t* lds) {
  __builtin_amdgcn_global_load_lds(
      (const __attribute__((address_space(1))) void*)g,
      (__attribute__((address_space(3))) void*)lds, 16, 0, 0);
}

// chunk swizzle for row-major [rows][64] bf16 tiles staged as 16B chunks
__device__ __forceinline__ int kchunk(int row, int kg) {
  return row * 8 + (kg ^ (row & 7));
}

// ---------------------------------------------------------------- fp32 -> bf16 (all 5 arrays)
__global__ __launch_bounds__(256) void cvt_all(
    const float* __restrict__ x, const float* __restrict__ rel,
    const float* __restrict__ wq, const float* __restrict__ wk, const float* __restrict__ wv,
    bf16_t* __restrict__ out) {
  const size_t i = ((size_t)blockIdx.x * 256 + threadIdx.x) * 4;
  const float* src; size_t off;
  if (i < 4194304) { src = x; off = i; }
  else {
    size_t j = i - 4194304; int sel = (int)(j >> 20); off = j & 1048575;
    src = sel == 0 ? wq : sel == 1 ? wk : sel == 2 ? wv : rel;
  }
  float4 v = *reinterpret_cast<const float4*>(src + off);
  bf16x4 o;
  o[0] = (bf16_t)v.x; o[1] = (bf16_t)v.y; o[2] = (bf16_t)v.z; o[3] = (bf16_t)v.w;
  *reinterpret_cast<bf16x4*>(out + i) = o;
}

// ------------------------------------------------- 256^2-tile 8-phase projection GEMM (R6)
__device__ __forceinline__ void stage_tile(const bf16_t* base, int T, bf16_t* lds, int tid) {
#pragma unroll
  for (int i = 0; i < 2; ++i) {
    const int c = tid + i * 512;
    const int row = c >> 2, kg = (c & 3) ^ (row & 3);
    gload_lds16(base + (size_t)row * 1024 + T * 32 + kg * 8, lds + c * 8);
  }
}

#define VMW2 asm volatile("s_waitcnt vmcnt(2)" ::: "memory")
#define VMW0 asm volatile("s_waitcnt vmcnt(0)" ::: "memory")
#define NOPS ((void)0)

#define PH_BODY(AB, BB, FH, READB, STAGE_STMT, WAIT_STMT)                               \
  {                                                                                     \
    if (READB) {                                                                        \
      _Pragma("unroll") for (int n_ = 0; n_ < 4; ++n_)                                  \
        bfr[n_] = *reinterpret_cast<const bf16x8*>(                                     \
            (BB) + (((wn * 64 + n_ * 16 + li) * 4 + (gr ^ (li & 3))) * 8));             \
    }                                                                                   \
    bf16x8 af_[4];                                                                      \
    _Pragma("unroll") for (int a_ = 0; a_ < 4; ++a_)                                    \
      af_[a_] = *reinterpret_cast<const bf16x8*>(                                       \
          (AB) + (((wm * 128 + ((FH) * 4 + a_) * 16 + li) * 4 + (gr ^ (li & 3))) * 8)); \
    STAGE_STMT;                                                                         \
    __builtin_amdgcn_s_barrier();                                                       \
    asm volatile("s_waitcnt lgkmcnt(0)" ::: "memory");                                  \
    __builtin_amdgcn_sched_barrier(0);                                                  \
    __builtin_amdgcn_s_setprio(1);                                                      \
    _Pragma("unroll") for (int a_ = 0; a_ < 4; ++a_)                                    \
      _Pragma("unroll") for (int n_ = 0; n_ < 4; ++n_)                                  \
        acc[(FH) * 4 + a_][n_] = MFMA16(af_[a_], bfr[n_], acc[(FH) * 4 + a_][n_]);      \
    __builtin_amdgcn_s_setprio(0);                                                      \
    WAIT_STMT;                                                                          \
    __builtin_amdgcn_s_barrier();                                                       \
    __builtin_amdgcn_sched_barrier(0);                                                  \
  }

__global__ __launch_bounds__(512, 2) void gemm_qkv(
    const bf16_t* __restrict__ xb, const bf16_t* __restrict__ reb,
    const bf16_t* __restrict__ wqb, const bf16_t* __restrict__ wkb, const bf16_t* __restrict__ wvb,
    const float* __restrict__ bq, const float* __restrict__ bk, const float* __restrict__ bv,
    bf16_t* __restrict__ qo, bf16_t* __restrict__ ko, bf16_t* __restrict__ vo,
    bf16_t* __restrict__ pko, bf16_t* __restrict__ pqo) {
  __shared__ bf16_t Abuf[2][8192];
  __shared__ bf16_t Bbuf[2][8192];

  const int bid0 = blockIdx.x;
  const int bid = (bid0 & 7) * 28 + (bid0 >> 3);  // 224 = 8*28, bijective XCD chunks
  const int tid = threadIdx.x;
  const int wave = tid >> 6;
  const int wm = wave >> 2, wn = wave & 3;
  const int l = tid & 63, li = l & 15, gr = l >> 4;

  const bf16_t* Abase; const bf16_t* Bbase; const float* bias; float sc;
  bf16_t* Cout; int row0, col0;
  if (bid < 192) {  // main: x (4096) x [Wq|Wk|Wv] (3072)
    const int bx = bid / 12, by = bid % 12;
    Abase = xb + (size_t)bx * 262144; row0 = bx * 256;
    const int wsel = by >> 2;
    Bbase = (wsel == 0 ? wqb : wsel == 1 ? wkb : wvb) + (size_t)(by & 3) * 262144;
    bias = wsel == 0 ? bq : wsel == 1 ? bk : bv;
    sc = wsel == 0 ? S2SCALE : 1.f;
    Cout = wsel == 0 ? qo : wsel == 1 ? ko : vo;
    col0 = (by & 3) * 256;
  } else {  // pos: re (1024) x [Wk|Wq] (2048)
    const int p = bid - 192;
    const int bx = p >> 3, by = p & 7;
    Abase = reb + (size_t)bx * 262144; row0 = bx * 256;
    const int wsel = by >> 2;
    Bbase = (wsel == 0 ? wkb : wqb) + (size_t)(by & 3) * 262144;
    bias = wsel == 0 ? bk : bq;
    sc = wsel == 0 ? 1.f : S2SCALE;
    Cout = wsel == 0 ? pko : pqo;
    col0 = (by & 3) * 256;
  }

  f32x4 acc[8][4] = {};
  bf16x8 bfr[4];

  stage_tile(Abase, 0, Abuf[0], tid);
  stage_tile(Bbase, 0, Bbuf[0], tid);
  stage_tile(Bbase, 1, Bbuf[1], tid);
  VMW2;
  __builtin_amdgcn_s_barrier();
  __builtin_amdgcn_sched_barrier(0);

  for (int t = 0; t < 15; ++t) {
    const int T0 = 2 * t;
    PH_BODY(Abuf[0], Bbuf[0], 0, true,  stage_tile(Abase, T0 + 1, Abuf[1], tid), NOPS);
    PH_BODY(Abuf[0], Bbuf[0], 1, false, stage_tile(Bbase, T0 + 2, Bbuf[0], tid), VMW2);
    PH_BODY(Abuf[1], Bbuf[1], 0, true,  stage_tile(Abase, T0 + 2, Abuf[0], tid), NOPS);
    PH_BODY(Abuf[1], Bbuf[1], 1, false, stage_tile(Bbase, T0 + 3, Bbuf[1], tid), VMW2);
  }
  PH_BODY(Abuf[0], Bbuf[0], 0, true,  stage_tile(Abase, 31, Abuf[1], tid), NOPS);
  PH_BODY(Abuf[0], Bbuf[0], 1, false, NOPS, VMW0);
  PH_BODY(Abuf[1], Bbuf[1], 0, true,  NOPS, NOPS);
  PH_BODY(Abuf[1], Bbuf[1], 1, false, NOPS, NOPS);

#pragma unroll
  for (int a = 0; a < 8; ++a)
#pragma unroll
    for (int n = 0; n < 4; ++n) {
      const int col = col0 + wn * 64 + n * 16 + li;
      const float bv_ = bias[col];
#pragma unroll
      for (int r = 0; r < 4; ++r) {
        const int row = row0 + wm * 128 + a * 16 + gr * 4 + r;
        Cout[(size_t)row * 1024 + col] = (bf16_t)((acc[a][n][r] + bv_) * sc);
      }
    }
}

// ---------------------------------------------------------------- fused attention + bias
// 512 blocks = (bh, qt-pair); 8 waves: qh = wave>>2 selects qt = 2*qp+qh, wv = wave&3
// owns 16 q-rows. pk/pq staged once per block as ring-of-4 64-row segments.
__global__ __launch_bounds__(512) void attn_mega(
    const bf16_t* __restrict__ qb, const bf16_t* __restrict__ kb,
    const bf16_t* __restrict__ vb, const bf16_t* __restrict__ pkb,
    const bf16_t* __restrict__ pqb, float* __restrict__ out) {
  const int bid0 = blockIdx.x;
  const int bid = (bid0 & 7) * 64 + (bid0 >> 3);  // 512 = 8*64, XCD chunks
  const int qp = bid & 3;
  const int bh = bid >> 2;
  const int h = bh & 15, b = bh >> 4;
  const int i0base = qp * 128;
  const int tid = threadIdx.x;
  const int w = tid >> 6, l = tid & 63;
  const int qh = w >> 2, wv = w & 3;
  const int li = l & 15, gr = l >> 4;
  const int i0 = i0base + qh * 64;

  __shared__ bf16_t Ks[2][4096];      // K tile dbuf, kchunk layout
  __shared__ bf16_t PKs[4][4096];     // pk ring: local seg s -> slot s&3
  __shared__ bf16_t PQs[4][4096];
  __shared__ bf16_t VT[4096];         // transposed V, chunk-swizzled
  __shared__ bf16_t Pl[8][1024];      // per-wave P A-frags
  __shared__ bf16_t D2c[2][64][72];   // c2p as [jj][ii] per qh (pad 72: +4-bank row skew)
  __shared__ bf16_t D2p[2][64][72];   // p2c as [jj][ii] per qh

  // stage one 64x64 tile (512 threads, 1 chunk each) into kchunk layout
#define STG(gsrc, lds) { int s_ = tid ^ ((tid >> 3) & 7);                              \
    gload_lds16((gsrc) + (size_t)(s_ >> 3) * 1024 + (s_ & 7) * 8, (lds) + tid * 8); }

  // Q fragments (direct global; q pre-scaled by S2SCALE)
  const bf16_t* qptr = qb + (size_t)(b * 512 + i0 + wv * 16 + li) * 1024 + h * 64 + gr * 8;
  const bf16x8 aq0 = *reinterpret_cast<const bf16x8*>(qptr);
  const bf16x8 aq1 = *reinterpret_cast<const bf16x8*>(qptr + 32);

  const bf16_t* kbase = kb + (size_t)(b * 512) * 1024 + h * 64;
  const bf16_t* vbase = vb + (size_t)(b * 512) * 1024 + h * 64;
  const bf16_t* pkw = pkb + (size_t)i0base * 1024 + h * 64;  // local row g: abs d = i0base+g
  const bf16_t* pqw = pqb + (size_t)i0base * 1024 + h * 64;

  f32x4 acc[4] = {};
  float lsum[4] = {0.f, 0.f, 0.f, 0.f};
  bf16x8 vreg[2];

  // prologue: K(0), pk/pq segs 7..9, V(0)
  STG(kbase, Ks[0]);
#pragma unroll
  for (int s = 7; s <= 9; ++s) {
    STG(pkw + (size_t)s * 65536, PKs[s & 3]);
    STG(pqw + (size_t)s * 65536, PQs[s & 3]);
  }
  vreg[0] = *reinterpret_cast<const bf16x8*>(vbase + (size_t)(tid >> 3) * 1024 + (tid & 7) * 8);
  asm volatile("s_waitcnt vmcnt(0)" ::: "memory");
  __builtin_amdgcn_s_barrier();
  __builtin_amdgcn_sched_barrier(0);

#pragma unroll
  for (int jt = 0; jt < 8; ++jt) {
    const int cur = jt & 1;
    const int sb = qh + 7 - jt;  // local seg index of this wave's window base

    if (jt) {  // arrival barrier (prefetched data landed; prev PV done)
      asm volatile("s_waitcnt vmcnt(0)" ::: "memory");
      __builtin_amdgcn_s_barrier();
      __builtin_amdgcn_sched_barrier(0);
    }

    // prefetch jt+1 (in flight across both mid barriers)
    if (jt < 7) {
      STG(kbase + (size_t)(jt + 1) * 65536, Ks[cur ^ 1]);
      const int sg = 6 - jt;
      STG(pkw + (size_t)sg * 65536, PKs[sg & 3]);
      STG(pqw + (size_t)sg * 65536, PQs[sg & 3]);
      vreg[cur ^ 1] = *reinterpret_cast<const bf16x8*>(
          vbase + (size_t)((jt + 1) * 64 + (tid >> 3)) * 1024 + (tid & 7) * 8);
    }

    // VT build from V regs
    {
      const int j = tid >> 3, w0 = (tid & 7) * 8;
      bf16x8 vv = vreg[cur];
#pragma unroll
      for (int e = 0; e < 8; ++e) {
        int ch = (j >> 3) * 64 + w0 + e;
        ch ^= ((ch >> 3) & 7);
        VT[ch * 8 + (j & 7)] = vv[e];
      }
    }

    __builtin_amdgcn_s_setprio(1);
    // QK^T
    f32x4 sfr[4];
#pragma unroll
    for (int n = 0; n < 4; ++n) {
      const int j_ = n * 16 + li;
      bf16x8 b0 = *reinterpret_cast<const bf16x8*>(Ks[cur] + kchunk(j_, gr) * 8);
      bf16x8 b1 = *reinterpret_cast<const bf16x8*>(Ks[cur] + kchunk(j_, 4 + gr) * 8);
      f32x4 t = {};
      t = MFMA16(aq0, b0, t);
      t = MFMA16(aq1, b1, t);
      sfr[n] = t;
    }

    // c2p strip: Dq[ii in wave strip][80-window], stored D2c[jj][ii]
#pragma unroll
    for (int cg = 0; cg < 5; ++cg) {
      const int b16 = wv + cg;
      const int slot = (sb + (b16 >> 2)) & 3;
      const int r64 = (b16 & 3) * 16 + li;
      bf16x8 p0 = *reinterpret_cast<const bf16x8*>(PKs[slot] + kchunk(r64, gr) * 8);
      bf16x8 p1 = *reinterpret_cast<const bf16x8*>(PKs[slot] + kchunk(r64, 4 + gr) * 8);
      f32x4 d = {};
      d = MFMA16(aq0, p0, d);
      d = MFMA16(aq1, p1, d);
#pragma unroll
      for (int r = 0; r < 4; ++r) {
        const int ip = gr * 4 + r;                // ii within strip
        const int jj = ip - (cg * 16 + li) + 63;  // jj = ii' - col + 63
        if ((unsigned)jj < 64u) D2c[qh][jj][wv * 16 + ip] = (bf16_t)d[r];
      }
    }

    // p2c strip: wave covers jj in [wv*16,+16), stored D2p[jj][ii]
    const bf16x8 ak0 = *reinterpret_cast<const bf16x8*>(Ks[cur] + kchunk(wv * 16 + li, gr) * 8);
    const bf16x8 ak1 = *reinterpret_cast<const bf16x8*>(Ks[cur] + kchunk(wv * 16 + li, 4 + gr) * 8);
#pragma unroll
    for (int cg = 0; cg < 5; ++cg) {
      const int b16 = 3 - wv + cg;
      const int slot = (sb + (b16 >> 2)) & 3;
      const int r64 = (b16 & 3) * 16 + li;
      bf16x8 p0 = *reinterpret_cast<const bf16x8*>(PQs[slot] + kchunk(r64, gr) * 8);
      bf16x8 p1 = *reinterpret_cast<const bf16x8*>(PQs[slot] + kchunk(r64, 4 + gr) * 8);
      f32x4 d = {};
      d = MFMA16(ak0, p0, d);
      d = MFMA16(ak1, p1, d);
#pragma unroll
      for (int r = 0; r < 4; ++r) {
        const int jp = gr * 4 + r;               // jj within strip
        const int iis = cg * 16 + li + jp - 15;  // ii = col + jj' - 15
        if ((unsigned)iis < 64u) D2p[qh][wv * 16 + jp][iis] = (bf16_t)d[r];
      }
    }
    __builtin_amdgcn_s_setprio(0);

    asm volatile("s_waitcnt lgkmcnt(0)" ::: "memory");
    __builtin_amdgcn_s_barrier();  // D2c/D2p + VT complete, cross-wave visible
    __builtin_amdgcn_sched_barrier(0);

    // gather biases (b64, conflict-free) + softmax + Pl
#pragma unroll
    for (int n = 0; n < 4; ++n) {
      const bf16x4 cvv = *reinterpret_cast<const bf16x4*>(&D2c[qh][n * 16 + li][wv * 16 + gr * 4]);
      const bf16x4 pvv = *reinterpret_cast<const bf16x4*>(&D2p[qh][n * 16 + li][wv * 16 + gr * 4]);
#pragma unroll
      for (int r = 0; r < 4; ++r) {
        const float s = sfr[n][r] + (float)cvv[r] + (float)pvv[r] - MCONST;
        const float pe = __builtin_amdgcn_exp2f(s);
        lsum[r] += pe;
        int ch = (n * 2 + (li >> 3)) * 16 + gr * 4 + r;
        ch ^= ((ch >> 3) & 7);
        Pl[w][ch * 8 + (li & 7)] = (bf16_t)pe;
      }
    }

    asm volatile("s_waitcnt lgkmcnt(0)" ::: "memory");
    __builtin_amdgcn_s_barrier();  // Pl ready; D2 reads done before next jt's writes
    __builtin_amdgcn_sched_barrier(0);

    // PV
    __builtin_amdgcn_s_setprio(1);
#pragma unroll
    for (int ks = 0; ks < 2; ++ks) {
      int chA = (ks * 4 + gr) * 16 + li;
      chA ^= ((chA >> 3) & 7);
      bf16x8 ap = *reinterpret_cast<const bf16x8*>(Pl[w] + chA * 8);
#pragma unroll
      for (int n2 = 0; n2 < 4; ++n2) {
        int chB = (ks * 4 + gr) * 64 + n2 * 16 + li;
        chB ^= ((chB >> 3) & 7);
        bf16x8 bvf = *reinterpret_cast<const bf16x8*>(VT + chB * 8);
        acc[n2] = MFMA16(ap, bvf, acc[n2]);
      }
    }
    __builtin_amdgcn_s_setprio(0);
  }
#undef STG

  // reduce lsum across the 16 li lanes, normalize, store
#pragma unroll
  for (int mm = 1; mm < 16; mm <<= 1)
#pragma unroll
    for (int r = 0; r < 4; ++r)
      lsum[r] += __shfl_xor(lsum[r], mm, 64);
  float invl[4];
#pragma unroll
  for (int r = 0; r < 4; ++r) invl[r] = 1.0f / lsum[r];

#pragma unroll
  for (int n2 = 0; n2 < 4; ++n2)
#pragma unroll
    for (int r = 0; r < 4; ++r) {
      const int i = i0 + wv * 16 + gr * 4 + r;
      const int wcol = n2 * 16 + li;
      out[(size_t)(b * 512 + i) * 1024 + h * 64 + wcol] = acc[n2][r] * invl[r];
    }
}

// ---------------------------------------------------------------- launch
extern "C" void kernel_launch(void* const* d_in, const int* in_sizes, int n_in,
                              void* d_out, int out_size, void* d_ws, size_t ws_size,
                              hipStream_t stream) {
  (void)in_sizes; (void)n_in; (void)out_size; (void)ws_size;
  const float* x   = (const float*)d_in[0];
  const float* rel = (const float*)d_in[1];
  const float* Wq  = (const float*)d_in[2];
  const float* bq  = (const float*)d_in[3];
  const float* Wk  = (const float*)d_in[4];
  const float* bk  = (const float*)d_in[5];
  const float* Wv  = (const float*)d_in[6];
  const float* bv  = (const float*)d_in[7];
  float* out = (float*)d_out;

  bf16_t* ws  = (bf16_t*)d_ws;
  bf16_t* xb  = ws;                 // 4 M elems
  bf16_t* wqb = xb + 4194304;       // 1 M each
  bf16_t* wkb = wqb + 1048576;
  bf16_t* wvb = wkb + 1048576;
  bf16_t* reb = wvb + 1048576;
  bf16_t* qbuf = reb + 1048576;     // 4 M each
  bf16_t* kbuf = qbuf + 4194304;
  bf16_t* vbuf = kbuf + 4194304;
  bf16_t* pkb = vbuf + 4194304;     // 1 M each
  bf16_t* pqb = pkb + 1048576;      // total ws ~44 MB

  cvt_all<<<8192, 256, 0, stream>>>(x, rel, Wq, Wk, Wv, ws);
  gemm_qkv<<<224, 512, 0, stream>>>(xb, reb, wqb, wkb, wvb,
                                    bq, bk, bv, qbuf, kbuf, vbuf, pkb, pqb);
  attn_mega<<<512, 512, 0, stream>>>(qbuf, kbuf, vbuf, pkb, pqb, out);
}